// Round 10
// baseline (80.045 us; speedup 1.0000x reference)
//
#include <hip/hip_runtime.h>
#include <math.h>

#define L      2048
#define DDIM   512
#define NBATCH 8
#define BM     256
#define BN     128
#define BK     64
#define NKT    (DDIM / BK)               // 8 K-tiles
#define NJT    (L / BM)                  // 8 j-tiles (256 rows)
#define NKTI   (L / BN)                  // 16 k-tiles (128 cols)
#define PAIRS  72                        // sum_{tj=0..7} (16 - 2*tj)
#define TOTAL_BLOCKS (NBATCH * PAIRS)    // 576

#define ALPHA  0.1f
#define BETA   0.3f
#define MARGIN 2.0f

typedef _Float16 f16x8 __attribute__((ext_vector_type(8)));
typedef __attribute__((ext_vector_type(16))) float f32x16;

// LDS ring: 3 buffers; buffer = A[256 rows x 64 f16] + B[128 rows x 64 f16]
// = 32KB + 16KB = 48KB. Rows are 128B = 8 chunks of 16B; physical chunk =
// logical ^ (row & 7)  (G4 conflict-free swizzle, proven in R8).
#define ABUF    16384      // f16: A tile
#define BUFSZ3  24576      // f16: A+B per buffer
#define LDS_BYTES (3 * BUFSZ3 * 2)   // 147456

#define GLOAD_LDS16(g, l) __builtin_amdgcn_global_load_lds(              \
    (const __attribute__((address_space(1))) unsigned int*)(g),          \
    (__attribute__((address_space(3))) unsigned int*)(l), 16, 0, 0)

// ---------------------------------------------------------------------------
// Kernel 1: fp32 -> fp16 + per-row squared norms (exact fp32).
// ---------------------------------------------------------------------------
__global__ __launch_bounds__(256) void conv_kernel(const float* __restrict__ pred,
                                                   _Float16* __restrict__ h,
                                                   float* __restrict__ sq) {
    int w    = threadIdx.x >> 6;
    int lane = threadIdx.x & 63;
    int row  = blockIdx.x * 4 + w;
    const float* p = pred + (size_t)row * DDIM + lane * 8;
    float4 v0 = *(const float4*)(p);
    float4 v1 = *(const float4*)(p + 4);
    float vals[8] = {v0.x, v0.y, v0.z, v0.w, v1.x, v1.y, v1.z, v1.w};
    f16x8 hv;
    float s = 0.0f;
    #pragma unroll
    for (int i = 0; i < 8; ++i) {
        float x = vals[i];
        s = fmaf(x, x, s);
        hv[i] = (_Float16)x;
    }
    *(f16x8*)(h + (size_t)row * DDIM + lane * 8) = hv;
    #pragma unroll
    for (int off = 32; off > 0; off >>= 1) s += __shfl_down(s, off);
    if (lane == 0) sq[row] = s;
}

// ---------------------------------------------------------------------------
// Kernel 2: fp16 Gram GEMM + fused loss + per-block reduction.
// 256x128 tile, 8 waves (4M x 2N, per-wave 64x64 = 2x2 frags of 32x32),
// mfma_f32_32x32x16_f16, BK=64, 8 K-tiles.
// 3-buffer LDS ring (144KB dynamic), depth-2 tile prefetch:
//   tile kt top: s_waitcnt vmcnt(6) (kt+1's 6 loads stay in flight; 0 only
//   at last tile) + ONE s_barrier; two half-phases each = {8 ds_read_b128,
//   3 global_load_lds of tile kt+2, setprio(1), 8 MFMA, setprio(0)}.
// ---------------------------------------------------------------------------
__global__ __launch_bounds__(512, 1) void loss_kernel(
        const _Float16* __restrict__ h,
        const int*   __restrict__ seg,
        const float* __restrict__ sq,
        double*      __restrict__ partials) {
    extern __shared__ _Float16 smem[];
    __shared__ double wred[8];

    int bid = blockIdx.x;
    int n = bid & 7;            // batch -> XCD round-robin (L2 locality)
    int p = bid >> 3;           // 0..71
    int tj = 0;                 // widths 16,14,...,2
    while (p >= NKTI - 2 * tj) { p -= NKTI - 2 * tj; ++tj; }
    int tk = 2 * tj + p;
    int j0 = tj * BM, k0 = tk * BN;

    int t    = threadIdx.x;
    int w    = t >> 6;          // 0..7
    int lane = t & 63;
    int wr   = w >> 1;          // 0..3: 64-row band of 256
    int wc   = w & 1;           // 0..1: 64-col band of 128
    int l31  = lane & 31;
    int hsel = lane >> 5;       // 0/1: k-halfslice of the frag

    const _Float16* baseH = h + (size_t)n * L * DDIM;

    // staging: instr covers 8 rows x 128B (1KB). lane -> row rl8=lane>>3,
    // physical chunk pc=lane&7, logical chunk lc = pc ^ rl8 (row&7 == rl8).
    int rl8 = lane >> 3;
    int lc  = (lane & 7) ^ rl8;
    const _Float16* srcA = baseH + (size_t)(j0 + rl8) * DDIM + lc * 8;
    const _Float16* srcB = baseH + (size_t)(k0 + rl8) * DDIM + lc * 8;

    f32x16 acc[2][2];
    #pragma unroll
    for (int m = 0; m < 2; ++m)
        #pragma unroll
        for (int nn = 0; nn < 2; ++nn)
            #pragma unroll
            for (int r = 0; r < 16; ++r) acc[m][nn][r] = 0.0f;

    // A insts: wave w -> {4w..4w+3} of 32 (rows inst*8..+7 of 256)
    // B insts: wave w -> {2w..2w+1} of 16 (rows inst*8..+7 of 128)
    #define STAGE_HALF(kt, half)                                              \
    {                                                                         \
        _Float16* _A = smem + ((kt) % 3) * BUFSZ3;                            \
        _Float16* _B = _A + ABUF;                                             \
        int _c0 = (kt) * BK;                                                  \
        int _qa = w * 4 + (half) * 2;                                         \
        int _qb = w * 2 + (half);                                             \
        GLOAD_LDS16(srcA + (size_t)((_qa + 0) * 8) * DDIM + _c0,              \
                    _A + (_qa + 0) * 512);                                    \
        GLOAD_LDS16(srcA + (size_t)((_qa + 1) * 8) * DDIM + _c0,              \
                    _A + (_qa + 1) * 512);                                    \
        GLOAD_LDS16(srcB + (size_t)(_qb * 8) * DDIM + _c0,                    \
                    _B + _qb * 512);                                          \
    }

    // prologue: tiles 0 and 1 fully staged (12 loads in flight)
    STAGE_HALF(0, 0); STAGE_HALF(0, 1);
    STAGE_HALF(1, 0); STAGE_HALF(1, 1);

    #pragma unroll
    for (int kt = 0; kt < NKT; ++kt) {
        // own tile-kt loads complete (kt+1's 6 remain in flight), then
        // block-wide barrier -> everyone's tile-kt data resident.
        if (kt + 1 < NKT) {
            asm volatile("s_waitcnt vmcnt(6)" ::: "memory");
        } else {
            asm volatile("s_waitcnt vmcnt(0)" ::: "memory");
        }
        __builtin_amdgcn_s_barrier();
        asm volatile("" ::: "memory");

        const _Float16* A = smem + (kt % 3) * BUFSZ3;
        const _Float16* B = A + ABUF;

        #pragma unroll
        for (int half = 0; half < 2; ++half) {
            // ds_read fragments for ks = 2*half, 2*half+1
            f16x8 a0[2], a1[2], b0[2], b1[2];
            int c0 = (2 * half) * 2 + hsel;       // logical chunk, ks even
            int c1 = (2 * half + 1) * 2 + hsel;   // ks odd
            #pragma unroll
            for (int m = 0; m < 2; ++m) {
                int R = wr * 64 + m * 32 + l31;
                int s7 = R & 7;
                a0[m] = *(const f16x8*)&A[R * 64 + ((c0 ^ s7) << 3)];
                a1[m] = *(const f16x8*)&A[R * 64 + ((c1 ^ s7) << 3)];
            }
            #pragma unroll
            for (int nn = 0; nn < 2; ++nn) {
                int R = wc * 64 + nn * 32 + l31;
                int s7 = R & 7;
                b0[nn] = *(const f16x8*)&B[R * 64 + ((c0 ^ s7) << 3)];
                b1[nn] = *(const f16x8*)&B[R * 64 + ((c1 ^ s7) << 3)];
            }
            // prefetch half of tile kt+2 (counted, stays in flight)
            if (kt + 2 < NKT) STAGE_HALF(kt + 2, half);
            asm volatile("" ::: "memory");

            __builtin_amdgcn_s_setprio(1);
            #pragma unroll
            for (int m = 0; m < 2; ++m)
                #pragma unroll
                for (int nn = 0; nn < 2; ++nn) {
                    acc[m][nn] = __builtin_amdgcn_mfma_f32_32x32x16_f16(
                        a0[m], b0[nn], acc[m][nn], 0, 0, 0);
                    acc[m][nn] = __builtin_amdgcn_mfma_f32_32x32x16_f16(
                        a1[m], b1[nn], acc[m][nn], 0, 0, 0);
                }
            __builtin_amdgcn_s_setprio(0);
        }
    }

    // ------------------- fused loss epilogue -------------------
    // 32x32 C/D layout: col = lane&31, row = (reg&3) + 8*(reg>>2) + 4*(lane>>5)
    const int*   segb = seg + n * L;
    const float* sqb  = sq + n * L;

    float lsum = 0.0f;    // weighted: skip j>k, 2x for j<k, 1x for j==k
    #pragma unroll
    for (int nn = 0; nn < 2; ++nn) {
        int k = k0 + wc * 64 + nn * 32 + l31;
        float sqk = sqb[k];
        int   sgk = segb[k];
        #pragma unroll
        for (int m = 0; m < 2; ++m)
            #pragma unroll
            for (int r = 0; r < 16; ++r) {
                int j = j0 + wr * 64 + m * 32 + (r & 3) + 8 * (r >> 2) + 4 * hsel;
                if (j > k) continue;
                float inner = acc[m][nn][r];
                float d2 = fmaxf(sqb[j] + sqk - 2.0f * inner, 0.0f);
                float v;
                if (segb[j] == sgk) {
                    v = ALPHA * d2;
                } else {
                    float dist = sqrtf(d2);
                    float hg = fmaxf(MARGIN - dist, 0.0f);
                    v = BETA * hg * hg;
                }
                lsum += (j < k) ? 2.0f * v : v;
            }
    }

    // per-wave shuffle reduction (no LDS tree -> no bank conflicts)
    double dsum = (double)lsum;
    #pragma unroll
    for (int off = 32; off > 0; off >>= 1)
        dsum += __shfl_down(dsum, off);
    if (lane == 0) wred[w] = dsum;
    __syncthreads();
    if (t == 0) {
        double s = ((wred[0] + wred[1]) + (wred[2] + wred[3]))
                 + ((wred[4] + wred[5]) + (wred[6] + wred[7]));
        partials[bid] = s;
    }
}

// ---------------------------------------------------------------------------
// Kernel 3: deterministic final reduction -> mean.
// ---------------------------------------------------------------------------
__global__ __launch_bounds__(256) void reduce_kernel(const double* __restrict__ partials,
                                                     float* __restrict__ out,
                                                     int nPart, double invCount) {
    __shared__ double red[256];
    int t = threadIdx.x;
    double s = 0.0;
    for (int i = t; i < nPart; i += 256) s += partials[i];
    red[t] = s;
    __syncthreads();
    #pragma unroll
    for (int k = 128; k > 0; k >>= 1) {
        if (t < k) red[t] += red[t + k];
        __syncthreads();
    }
    if (t == 0) out[0] = (float)(red[0] * invCount);
}

extern "C" void kernel_launch(void* const* d_in, const int* in_sizes, int n_in,
                              void* d_out, int out_size, void* d_ws, size_t ws_size,
                              hipStream_t stream) {
    const float* pred = (const float*)d_in[0];
    const int*   seg  = (const int*)d_in[1];
    float* out = (float*)d_out;

    const size_t HALF = (size_t)NBATCH * L * DDIM;
    _Float16* h        = (_Float16*)d_ws;                    // 16.78 MB
    float*    sq       = (float*)(h + HALF);                 // 64 KB
    double*   partials = (double*)(sq + NBATCH * L);         // 4.6 KB

    // allow 144KB dynamic LDS (idempotent; not a stream operation)
    (void)hipFuncSetAttribute((const void*)loss_kernel,
                              hipFuncAttributeMaxDynamicSharedMemorySize,
                              LDS_BYTES);

    conv_kernel<<<NBATCH * L / 4, 256, 0, stream>>>(pred, h, sq);
    loss_kernel<<<TOTAL_BLOCKS, 512, LDS_BYTES, stream>>>(h, seg, sq, partials);
    reduce_kernel<<<1, 256, 0, stream>>>(partials, out, TOTAL_BLOCKS,
                                         1.0 / (double)((size_t)NBATCH * L * L));
}